// Round 10
// baseline (84.834 us; speedup 1.0000x reference)
//
#include <hip/hip_runtime.h>
#include <math.h>

// Problem constants (fixed by the reference setup)
#define B_ 32
#define N_ 2048
#define D_ 64
#define R_ 32
#define T_ 31
#define O_ 12
#define HID_ 128
#define IN_DIM_ 63      // T_ + R_
#define NCH_ 32         // n-chunks for partial-U reduction

// Workspace layout (float offsets)
#define OFF_UPART 0                                  // B*NCH*R*D = 2,097,152 floats
#define OFF_PBF   (OFF_UPART + B_*NCH_*R_*D_)        // bf16 area: N*R ushort = 32,768 floats
#define OFF_SUT   (OFF_PBF + N_*R_/2)                // bf16 area: B*O*D*R ushort = 393,216 floats
// end ~ 2.52M floats ~ 10.1 MB (< ws)

typedef __attribute__((ext_vector_type(4))) float f32x4;
typedef __attribute__((ext_vector_type(8))) short short8;

__device__ __forceinline__ float softplus_f(float x) {
    return fmaxf(x, 0.0f) + log1pf(expf(-fabsf(x)));
}
__device__ __forceinline__ float gelu_f(float x) {
    return 0.5f * x * (1.0f + erff(x * 0.70710678118654752440f));
}
// float -> bf16 bits, round-to-nearest-even
__device__ __forceinline__ unsigned short f2bf(float f) {
    unsigned int u = __float_as_uint(f);
    u = (u + 0x7FFFu + ((u >> 16) & 1u)) >> 16;
    return (unsigned short)u;
}

// Kernel 1 (k_front): softplus(Q) fused into the partial-U pass.
// grid = B_*NCH_ = 1024 blocks, 512 threads (8 waves). Wave w owns r0=w*4.
// Each lane pre-computes softplus(Q[n0+lane][r0..r0+3]) into 4 VGPRs; the
// inner loop broadcasts lane i's values via v_readlane (uniform index ->
// SGPR fmac operand). No LDS, no scalar-cache dependence, no extra kernel.
// b==0 blocks also emit Pbf = bf16(softplus(P_raw)) for their n-chunk.
__global__ __launch_bounds__(512) void k_front(const float* __restrict__ H,
                                               const float* __restrict__ Qr,
                                               const float* __restrict__ Pr,
                                               float* __restrict__ ws) {
    float* __restrict__ Upart = ws + OFF_UPART;
    int b = blockIdx.x / NCH_;
    int c = blockIdx.x % NCH_;
    int tid = threadIdx.x;
    int lane = tid & 63;
    int w = __builtin_amdgcn_readfirstlane(tid >> 6);  // 0..7, wave-uniform
    const int r0 = w * 4;
    const int n0 = c * 64;

    if (b == 0) {
        unsigned short* Pbf = (unsigned short*)(ws + OFF_PBF);
        for (int i = tid; i < 64 * R_; i += 512)
            Pbf[(size_t)n0 * R_ + i] = f2bf(softplus_f(Pr[(size_t)n0 * R_ + i]));
    }

    // Per-lane softplus of this wave's Q slice: lane l holds row n0+l, r0..r0+3
    const float* qrow = Qr + (size_t)(n0 + lane) * R_ + r0;
    float q0 = softplus_f(qrow[0]);
    float q1 = softplus_f(qrow[1]);
    float q2 = softplus_f(qrow[2]);
    float q3 = softplus_f(qrow[3]);

    float acc0 = 0.f, acc1 = 0.f, acc2 = 0.f, acc3 = 0.f;
    const float* __restrict__ Hb = H + ((size_t)b * N_ + n0) * D_ + lane;
    #pragma unroll 4
    for (int i = 0; i < 64; ++i) {
        float h = Hb[(size_t)i * D_];
        float s0 = __int_as_float(__builtin_amdgcn_readlane(__float_as_int(q0), i));
        float s1 = __int_as_float(__builtin_amdgcn_readlane(__float_as_int(q1), i));
        float s2 = __int_as_float(__builtin_amdgcn_readlane(__float_as_int(q2), i));
        float s3 = __int_as_float(__builtin_amdgcn_readlane(__float_as_int(q3), i));
        acc0 = fmaf(h, s0, acc0);
        acc1 = fmaf(h, s1, acc1);
        acc2 = fmaf(h, s2, acc2);
        acc3 = fmaf(h, s3, acc3);
    }
    float* up = Upart + ((size_t)(b * NCH_ + c) * R_ + r0) * D_ + lane;
    up[0 * D_] = acc0;
    up[1 * D_] = acc1;
    up[2 * D_] = acc2;
    up[3 * D_] = acc3;
}

// Kernel 2 (k_tail): fused ured + ctx + MLP + SUT. grid = B_ = 32 blocks, 512 thr.
// Phase 1: reduce Upart -> U in LDS (f32x4 per thread), ctx via 16-lane shuffle.
// Phase 2: MLP — 4 groups of 128 threads; group g does o = g, g+4, g+8.
// Phase 3: SUT[b,o][d][r] = bf16(a * s[o][r] * U[r][d]).
__global__ __launch_bounds__(512) void k_tail(const float* __restrict__ ts_out,
                                              const float* __restrict__ W1,
                                              const float* __restrict__ b1,
                                              const float* __restrict__ W2,
                                              const float* __restrict__ b2,
                                              const float* __restrict__ alpha,
                                              float* __restrict__ ws) {
    __shared__ float Ul[R_][D_];        // 8 KB
    __shared__ float ctxl[R_];
    __shared__ float tsl[O_ * T_];      // 372 floats
    __shared__ float hsh[O_][HID_];     // 6 KB
    __shared__ float ssh[O_][R_];       // 1.5 KB
    int b = blockIdx.x;
    int tid = threadIdx.x;
    const float* __restrict__ Upart = ws + OFF_UPART;

    // Phase 1: U reduce + ctx
    {
        int r = tid >> 4;            // 0..31
        int d0 = (tid & 15) * 4;     // 0,4,..,60
        f32x4 u = {0.f, 0.f, 0.f, 0.f};
        #pragma unroll 8
        for (int c = 0; c < NCH_; ++c)
            u += *(const f32x4*)(Upart + ((size_t)(b * NCH_ + c) * R_ + r) * D_ + d0);
        *(f32x4*)(&Ul[r][d0]) = u;
        float sq = u[0]*u[0] + u[1]*u[1] + u[2]*u[2] + u[3]*u[3];
        #pragma unroll
        for (int off = 8; off; off >>= 1) sq += __shfl_xor(sq, off, 16);
        if ((tid & 15) == 0) ctxl[r] = sqrtf(sq * (1.0f / D_) + 1e-6f);
    }
    // stage ts_out rows for this b (feat[0..30] per o)
    for (int i = tid; i < O_ * T_; i += 512)
        tsl[i] = ts_out[(size_t)b * O_ * T_ + i];
    __syncthreads();

    // Phase 2: MLP
    int g = tid >> 7;       // 0..3
    int lt = tid & 127;     // hidden neuron
    #pragma unroll
    for (int oo = 0; oo < 3; ++oo) {
        int o = g + oo * 4;
        float acc = b1[lt];
        for (int k = 0; k < T_; ++k) acc = fmaf(tsl[o * T_ + k], W1[k * HID_ + lt], acc);
        for (int k = 0; k < R_; ++k) acc = fmaf(ctxl[k], W1[(T_ + k) * HID_ + lt], acc);
        hsh[o][lt] = gelu_f(acc);
    }
    __syncthreads();
    if (tid < O_ * R_) {
        int o = tid >> 5, r = tid & 31;
        float a2 = b2[r];
        #pragma unroll 8
        for (int j = 0; j < HID_; ++j) a2 = fmaf(hsh[o][j], W2[j * R_ + r], a2);
        ssh[o][r] = softplus_f(a2);
    }
    __syncthreads();

    // Phase 3: SUT (bf16, [o][d][r]) — coalesced 2B stores, r fastest
    float a = fminf(fmaxf(alpha[0], 0.0f), 1.0f);
    unsigned short* SUT = (unsigned short*)(ws + OFF_SUT) + (size_t)b * O_ * D_ * R_;
    for (int idx = tid; idx < O_ * D_ * R_; idx += 512) {
        int r = idx & 31, d = (idx >> 5) & 63, o = idx >> 11;
        SUT[idx] = f2bf(a * ssh[o][r] * Ul[r][d]);
    }
}

// Kernel 3 (k_main, unchanged R9): MFMA + wave-local LDS transpose, no barriers.
//   D[d][n] = sum_r SUT[b,o][d][r] * P[n][r];  out[b,o,n,d] = oma*H + D
// grid (N/64, B), block 256 (4 waves).
__global__ __launch_bounds__(256) void k_main(const float* __restrict__ H,
                                              const float* __restrict__ alpha,
                                              const float* __restrict__ ws,
                                              float* __restrict__ out) {
    __shared__ float tile[2 * 64 * 64];   // 32 KB: two halves, wave-sliced
    const int b = blockIdx.y;
    const int nblk = blockIdx.x * 64;
    const int tid = threadIdx.x;
    const int w = tid >> 6;
    const int lane = tid & 63;
    const int l16 = lane & 15;
    const int lhi = lane >> 4;
    const int rl = w * 16 + l16;
    const float a = fminf(fmaxf(alpha[0], 0.0f), 1.0f);
    const float oma = 1.0f - a;

    const unsigned short* Pbf = (const unsigned short*)(ws + OFF_PBF);
    const unsigned short* SUT0 = (const unsigned short*)(ws + OFF_SUT);

    short8 pfrag = *(const short8*)(Pbf + (size_t)(nblk + rl) * R_ + lhi * 8);

    const float* __restrict__ Hrow = H + ((size_t)b * N_ + nblk + rl) * D_;
    f32x4 homa[4];
    #pragma unroll
    for (int db = 0; db < 4; ++db)
        homa[db] = oma * *(const f32x4*)(Hrow + db * 16 + lhi * 4);

    char* t0 = (char*)tile;
    char* t1 = (char*)tile + 16384;
    float* __restrict__ oblk = out + ((size_t)(b * O_) * N_ + nblk) * D_;

    for (int o = 0; o < O_; o += 2) {
        const unsigned short* S0 = SUT0 + (size_t)(b * O_ + o) * D_ * R_;
        const unsigned short* S1 = S0 + D_ * R_;
        short8 sf[8];
        #pragma unroll
        for (int db = 0; db < 4; ++db) {
            sf[db]     = *(const short8*)(S0 + (size_t)(db * 16 + l16) * R_ + lhi * 8);
            sf[4 + db] = *(const short8*)(S1 + (size_t)(db * 16 + l16) * R_ + lhi * 8);
        }
        #pragma unroll
        for (int h = 0; h < 2; ++h) {
            char* tb = h ? t1 : t0;
            #pragma unroll
            for (int db = 0; db < 4; ++db) {
                f32x4 v = homa[db] + __builtin_amdgcn_mfma_f32_16x16x32_bf16(
                    sf[h * 4 + db], pfrag, (f32x4){0.f, 0.f, 0.f, 0.f}, 0, 0, 0);
                int c = (db * 64 + lhi * 16) ^ ((rl & 7) << 4);
                *(f32x4*)(tb + rl * 256 + c) = v;
            }
        }
        #pragma unroll
        for (int h = 0; h < 2; ++h) {
            char* tb = h ? t1 : t0;
            char* op = (char*)(oblk + (size_t)(o + h) * N_ * D_);
            #pragma unroll
            for (int i = 0; i < 4; ++i) {
                int gg = w * 4096 + i * 1024 + lane * 16;
                int rr = gg >> 8;
                int cc = (gg & 255) ^ ((rr & 7) << 4);
                f32x4 v = *(const f32x4*)(tb + rr * 256 + cc);
                *(f32x4*)(op + gg) = v;
            }
        }
    }
}

extern "C" void kernel_launch(void* const* d_in, const int* in_sizes, int n_in,
                              void* d_out, int out_size, void* d_ws, size_t ws_size,
                              hipStream_t stream) {
    const float* H      = (const float*)d_in[0];
    const float* ts_out = (const float*)d_in[1];
    // d_in[2] is O (int scalar) — shapes are compile-time constants here
    const float* P_raw  = (const float*)d_in[3];
    const float* Q_raw  = (const float*)d_in[4];
    const float* W1     = (const float*)d_in[5];
    const float* b1     = (const float*)d_in[6];
    const float* W2     = (const float*)d_in[7];
    const float* b2     = (const float*)d_in[8];
    const float* alpha  = (const float*)d_in[9];
    float* out = (float*)d_out;
    float* ws  = (float*)d_ws;

    // 1. fused softplus + partial U (+Pbf from b==0 blocks)
    k_front<<<dim3(B_ * NCH_), dim3(512), 0, stream>>>(H, Q_raw, P_raw, ws);
    // 2. fused reduce + ctx + MLP + SUT
    k_tail<<<dim3(B_), dim3(512), 0, stream>>>(ts_out, W1, b1, W2, b2, alpha, ws);
    // 3. main fused output via MFMA + wave-local LDS transpose
    k_main<<<dim3(N_ / 64, B_), dim3(256), 0, stream>>>(H, alpha, ws, out);
}